// Round 7
// baseline (301.703 us; speedup 1.0000x reference)
//
#include <hip/hip_runtime.h>
#include <hip/hip_bf16.h>
#include <math.h>

typedef __hip_bfloat16 bf16;
typedef __attribute__((ext_vector_type(8))) short short8;
typedef __attribute__((ext_vector_type(4))) float floatx4;
typedef __attribute__((ext_vector_type(4))) unsigned int uint4v;
typedef __attribute__((ext_vector_type(2))) unsigned int uint2v;

#define HW 16384          // 128*128
#define NSLICE 243        // 9*9*3

// ---- band tables (anti-diagonals of 9x9 grid) ----
__constant__ int c_s_of_p[81] = {
  0, 1,1, 2,2,2, 3,3,3,3, 4,4,4,4,4, 5,5,5,5,5,5, 6,6,6,6,6,6,6,
  7,7,7,7,7,7,7,7, 8,8,8,8,8,8,8,8,8, 9,9,9,9,9,9,9,9,
  10,10,10,10,10,10,10, 11,11,11,11,11,11, 12,12,12,12,12,
  13,13,13,13, 14,14,14, 15,15, 16};
__constant__ int c_l_of_p[81] = {
  0, 0,1, 0,1,2, 0,1,2,3, 0,1,2,3,4, 0,1,2,3,4,5, 0,1,2,3,4,5,6,
  0,1,2,3,4,5,6,7, 0,1,2,3,4,5,6,7,8, 0,1,2,3,4,5,6,7,
  0,1,2,3,4,5,6, 0,1,2,3,4,5, 0,1,2,3,4, 0,1,2,3, 0,1,2, 0,1, 0};
__constant__ int c_L_of_s[17] = {1,2,3,4,5,6,7,8,9,8,7,6,5,4,3,2,1};
__constant__ int c_g_of_s[17] = {0,1,1,2,2,2,2,2,2,3,3,3,3,3,3,3,3};
__constant__ int c_pos_uv[81] = {
  0,1,3,6,10,15,21,28,36,
  2,4,7,11,16,22,29,37,45,
  5,8,12,17,23,30,38,46,53,
  9,13,18,24,31,39,47,54,60,
  14,19,25,32,40,48,55,61,66,
  20,26,33,41,49,56,62,67,71,
  27,34,42,50,57,63,68,72,75,
  35,43,51,58,64,69,73,76,78,
  44,52,59,65,70,74,77,79,80};

struct WPtrs {
  const float* wi[4]; const float* bi[4]; const float* a[4];
  const float* wb[4]; const float* bb[4]; const float* wl;
};

__device__ __forceinline__ unsigned short f2bf(float f) {
  return __bfloat16_as_ushort(__float2bfloat16(f));
}
__device__ __forceinline__ float bflo(unsigned int w) {
  return __uint_as_float(w << 16);
}
__device__ __forceinline__ float bfhi(unsigned int w) {
  return __uint_as_float(w & 0xffff0000u);
}
__device__ __forceinline__ unsigned int pack2(float a, float b) {
  return (unsigned int)f2bf(a) | ((unsigned int)f2bf(b) << 16);
}
// inverse PReLU: raw = v>=0 ? v : v*invA  (exact for alpha = power of two)
__device__ __forceinline__ float invprelu(float v, float invA) {
  return (v >= 0.f) ? v : v * invA;
}
// split fp32 into bf16 hi (truncate) + bf16 lo (RNE of remainder): ~2^-17 rel
__device__ __forceinline__ void bfsplit(float v, unsigned short& hi, unsigned short& lo) {
  unsigned int bits = __float_as_uint(v);
  hi = (unsigned short)(bits >> 16);
  lo = f2bf(v - __uint_as_float(bits & 0xffff0000u));
}
// async global->LDS 16B: LDS dest = wave-uniform base + lane*16
__device__ __forceinline__ void gl_lds16(const void* g, void* l) {
  __builtin_amdgcn_global_load_lds(
      (const __attribute__((address_space(1))) unsigned int*)g,
      (__attribute__((address_space(3))) unsigned int*)l, 16, 0, 0);
}

// ---- setup: 9-point angular DCT matrix + spatial-DCT MFMA fragment tables ----
__global__ __launch_bounds__(256) void k_setup(float* DaF,
                                               unsigned short* TFhi, unsigned short* TFlo,
                                               unsigned short* TIhi, unsigned short* TIlo) {
  const double PI = 3.14159265358979323846;
  int t = blockIdx.x * 256 + threadIdx.x;
  if (t < 81) {   // Da[U][u]
    int U = t / 9, u = t % 9;
    double d = cos(PI * (u + 0.5) * U / 9.0) * sqrt(2.0 / 9.0);
    if (U == 0) d *= (1.0 / sqrt(2.0));
    DaF[t] = (float)d;
  }
  if (t < 16384) {
    int jj = t & 7, lane = (t >> 3) & 63, ks = (t >> 9) & 3, tile = t >> 11;
    int row = tile * 16 + (lane & 15);
    int colk = ks * 32 + (lane >> 4) * 8 + jj;
    double vF = cos(PI * (colk + 0.5) * row / 128.0) * sqrt(2.0 / 128.0);
    if (row == 0) vF *= (1.0 / sqrt(2.0));
    double vI = cos(PI * (row + 0.5) * colk / 128.0) * sqrt(2.0 / 128.0);
    if (colk == 0) vI *= (1.0 / sqrt(2.0));
    unsigned short h, l;
    bfsplit((float)vF, h, l); TFhi[t] = h; TFlo[t] = l;
    bfsplit((float)vI, h, l); TIhi[t] = h; TIlo[t] = l;
  }
}

// ---- conv weight repack into MFMA A-fragment order (unchanged) ----
__global__ __launch_bounds__(256) void k_prep(WPtrs P, unsigned short* Wmf,
                                              float* BiF, float* BbF,
                                              float* AF, float* WlF) {
  int t = blockIdx.x * 256 + threadIdx.x;
  if (t < 92160) {
    int s = t / 7680, r = t % 7680;
    int step = r / 512, r2 = r % 512;
    int lane = r2 >> 3, j = r2 & 7;
    int d = step / 5, i = step % 5;
    int q = lane >> 4, m = lane & 15;
    int tl = 2 * i + (q >> 1);
    int cin = (q & 1) * 8 + j;
    float val = 0.f;
    if (tl <= 8) {
      int ky = tl / 3, kx = tl % 3;
      int tap = d * 9 + ky * 3 + kx;
      if (s < 4) {
        if (cin < 3) val = P.wi[s][(m * 3 + cin) * 27 + tap];
      } else {
        int g = (s - 4) >> 1, k = (s - 4) & 1;
        val = P.wb[g][((k * 16 + m) * 16 + cin) * 27 + tap];
      }
    }
    Wmf[t] = f2bf(val);
  }
  if (t < 64)  BiF[t] = P.bi[t / 16][t % 16];
  if (t < 128) BbF[t] = P.bb[t / 32][t % 32];
  if (t < 8)   AF[t]  = P.a[t / 2][t % 2];
  if (t < 48)  WlF[t] = P.wl[t];
}

// ---- fused spatial DCT: Y = Dop * X * Dop^T per 128x128 slice (unchanged) ----
__global__ __launch_bounds__(256) void k_dct2(const float* __restrict__ X,
                                              const unsigned short* __restrict__ tabhi,
                                              const unsigned short* __restrict__ tablo,
                                              const float* __restrict__ xres,
                                              float* __restrict__ Y) {
  __shared__ unsigned short sThi[128 * 136];
  __shared__ unsigned short sTlo[128 * 136];
  int s = blockIdx.x;
  int t = threadIdx.x;
  int lane = t & 63, wv = t >> 6;
  int q = lane >> 4, n16 = lane & 15;
  const float* Xs = X + (size_t)s * HW;

  floatx4 acc[2][8];
#pragma unroll
  for (int mt = 0; mt < 2; mt++)
#pragma unroll
    for (int nt = 0; nt < 8; nt++) acc[mt][nt] = (floatx4){0.f, 0.f, 0.f, 0.f};

#pragma unroll
  for (int ks = 0; ks < 4; ks++) {
    short8 ahi[2], alo[2];
#pragma unroll
    for (int mt = 0; mt < 2; mt++) {
      const float* xp = Xs + (wv * 32 + mt * 16 + n16) * 128 + ks * 32 + q * 8;
      float4 a = *(const float4*)xp;
      float4 b = *(const float4*)(xp + 4);
      union { short8 v; unsigned short u[8]; } H, L;
      float xv[8] = {a.x, a.y, a.z, a.w, b.x, b.y, b.z, b.w};
#pragma unroll
      for (int j = 0; j < 8; j++) bfsplit(xv[j], H.u[j], L.u[j]);
      ahi[mt] = H.v; alo[mt] = L.v;
    }
#pragma unroll
    for (int nt = 0; nt < 8; nt++) {
      int e = nt * 2048 + ks * 512 + lane * 8;
      short8 bh = *(const short8*)(tabhi + e);
      short8 bl = *(const short8*)(tablo + e);
#pragma unroll
      for (int mt = 0; mt < 2; mt++) {
        acc[mt][nt] = __builtin_amdgcn_mfma_f32_16x16x32_bf16(ahi[mt], bl, acc[mt][nt], 0, 0, 0);
        acc[mt][nt] = __builtin_amdgcn_mfma_f32_16x16x32_bf16(alo[mt], bh, acc[mt][nt], 0, 0, 0);
        acc[mt][nt] = __builtin_amdgcn_mfma_f32_16x16x32_bf16(ahi[mt], bh, acc[mt][nt], 0, 0, 0);
      }
    }
  }

#pragma unroll
  for (int mt = 0; mt < 2; mt++)
#pragma unroll
    for (int nt = 0; nt < 8; nt++) {
      int col = nt * 16 + n16;
      int rowb = wv * 32 + mt * 16 + q * 4;
#pragma unroll
      for (int rp = 0; rp < 4; rp += 2) {
        unsigned short h0, l0, h1, l1;
        bfsplit(acc[mt][nt][rp], h0, l0);
        bfsplit(acc[mt][nt][rp + 1], h1, l1);
        int widx = (col * 136 + rowb + rp) >> 1;
        ((unsigned int*)sThi)[widx] = (unsigned int)h0 | ((unsigned int)h1 << 16);
        ((unsigned int*)sTlo)[widx] = (unsigned int)l0 | ((unsigned int)l1 << 16);
      }
    }
  __syncthreads();

#pragma unroll
  for (int mt = 0; mt < 2; mt++)
#pragma unroll
    for (int nt = 0; nt < 8; nt++) acc[mt][nt] = (floatx4){0.f, 0.f, 0.f, 0.f};

#pragma unroll
  for (int ks = 0; ks < 4; ks++) {
    short8 ahi[2], alo[2];
#pragma unroll
    for (int mt = 0; mt < 2; mt++) {
      int e = (wv * 2 + mt) * 2048 + ks * 512 + lane * 8;
      ahi[mt] = *(const short8*)(tabhi + e);
      alo[mt] = *(const short8*)(tablo + e);
    }
#pragma unroll
    for (int nt = 0; nt < 8; nt++) {
      int off = (nt * 16 + n16) * 136 + ks * 32 + q * 8;
      short8 bh = *(const short8*)(sThi + off);
      short8 bl = *(const short8*)(sTlo + off);
#pragma unroll
      for (int mt = 0; mt < 2; mt++) {
        acc[mt][nt] = __builtin_amdgcn_mfma_f32_16x16x32_bf16(ahi[mt], bl, acc[mt][nt], 0, 0, 0);
        acc[mt][nt] = __builtin_amdgcn_mfma_f32_16x16x32_bf16(alo[mt], bh, acc[mt][nt], 0, 0, 0);
        acc[mt][nt] = __builtin_amdgcn_mfma_f32_16x16x32_bf16(ahi[mt], bh, acc[mt][nt], 0, 0, 0);
      }
    }
  }

#pragma unroll
  for (int mt = 0; mt < 2; mt++)
#pragma unroll
    for (int nt = 0; nt < 8; nt++) {
      int row0 = wv * 32 + mt * 16 + q * 4;
      int col = nt * 16 + n16;
#pragma unroll
      for (int r = 0; r < 4; r++) {
        size_t oi = (size_t)s * HW + (size_t)(row0 + r) * 128 + col;
        float v = acc[mt][nt][r];
        if (xres) v += xres[oi];
        Y[oi] = v;
      }
    }
}

// ---- fused forward angular DCT (both 9-pt passes in one kernel) ----
// Block: 128 threads, 128 hw positions, one c. LDS columns are thread-private
// (thread t owns slot t of every plane) -> no syncs, no spill.
__global__ __launch_bounds__(128) void k_angF(const float* __restrict__ xf1,
                                              const float* __restrict__ DaF,
                                              unsigned short* __restrict__ xf2b) {
  __shared__ float L[81 * 128];
  __shared__ float sDa[81];
  int t = threadIdx.x;
  int c = blockIdx.y;
  int hw = blockIdx.x * 128 + t;
  if (t < 81) sDa[t] = DaF[t];
  __syncthreads();
#pragma unroll 3
  for (int i = 0; i < 81; i++)
    L[i * 128 + t] = xf1[(size_t)(i * 3 + c) * HW + hw];
  // pass 1: u-direction (in-place per column)
  for (int v = 0; v < 9; v++) {
    float f[9];
#pragma unroll
    for (int u = 0; u < 9; u++) f[u] = L[(u * 9 + v) * 128 + t];
#pragma unroll
    for (int U = 0; U < 9; U++) {
      float a = 0.f;
#pragma unroll
      for (int u = 0; u < 9; u++) a += sDa[U * 9 + u] * f[u];
      L[(U * 9 + v) * 128 + t] = a;
    }
  }
  // pass 2: v-direction + band gather + bf16 pack (channels-last padded-4)
  for (int U = 0; U < 9; U++) {
    float f[9];
#pragma unroll
    for (int v = 0; v < 9; v++) f[v] = L[(U * 9 + v) * 128 + t];
#pragma unroll
    for (int V = 0; V < 9; V++) {
      float a = 0.f;
#pragma unroll
      for (int v = 0; v < 9; v++) a += sDa[V * 9 + v] * f[v];
      size_t base = ((size_t)c_pos_uv[U * 9 + V] * HW + hw) * 4;
      xf2b[base + c] = f2bf(a);
      if (c == 0) xf2b[base + 3] = 0;
    }
  }
}

// ---- fused inverse angular DCT (band scatter read, both passes) ----
__global__ __launch_bounds__(128) void k_angI(const float* __restrict__ xrb,
                                              const float* __restrict__ DaF,
                                              float* __restrict__ xr2) {
  __shared__ float L[81 * 128];
  __shared__ float sDa[81];
  int t = threadIdx.x;
  int c = blockIdx.y;
  int hw = blockIdx.x * 128 + t;
  if (t < 81) sDa[t] = DaF[t];
  __syncthreads();
#pragma unroll 3
  for (int i = 0; i < 81; i++)   // i = U*9+V
    L[i * 128 + t] = xrb[((size_t)c_pos_uv[i] * 3 + c) * HW + hw];
  // pass 1: V -> v
  for (int U = 0; U < 9; U++) {
    float f[9];
#pragma unroll
    for (int V = 0; V < 9; V++) f[V] = L[(U * 9 + V) * 128 + t];
#pragma unroll
    for (int v = 0; v < 9; v++) {
      float a = 0.f;
#pragma unroll
      for (int V = 0; V < 9; V++) a += sDa[V * 9 + v] * f[V];
      L[(U * 9 + v) * 128 + t] = a;
    }
  }
  // pass 2: U -> u, write slices
  for (int v = 0; v < 9; v++) {
    float f[9];
#pragma unroll
    for (int U = 0; U < 9; U++) f[U] = L[(U * 9 + v) * 128 + t];
#pragma unroll
    for (int u = 0; u < 9; u++) {
      float a = 0.f;
#pragma unroll
      for (int U = 0; U < 9; U++) a += sDa[U * 9 + u] * f[U];
      xr2[(size_t)((u * 9 + v) * 3 + c) * HW + hw] = a;
    }
  }
}

// ---- MFMA implicit-GEMM 3x3x3 conv, 8 output rows per 512-thread block ----
// Res convs stage via async global_load_lds (wave-uniform base + lane*16),
// removing the ds_write + VGPR round-trip. OOB rows pre-zeroed once.
__global__ __launch_bounds__(512) void k_conv(const unsigned short* __restrict__ src,
                                              const unsigned short* __restrict__ prevAct,
                                              const unsigned short* __restrict__ act0,
                                              const unsigned short* __restrict__ Wmf,
                                              const float* __restrict__ BiF,
                                              const float* __restrict__ BbF,
                                              const float* __restrict__ AF,
                                              const float* __restrict__ WlF,
                                              int sel,
                                              unsigned short* __restrict__ boutAct,
                                              float* __restrict__ xrbOut) {
  __shared__ unsigned short s_lds[10 * 132 * 16];   // 42240 B
  int p = blockIdx.y;
  int s = c_s_of_p[p], l = c_l_of_p[p];
  int g = c_g_of_s[s], Ls = c_L_of_s[s];
  int row0 = blockIdx.x * 8;
  int t = threadIdx.x;
  int lane = t & 63, wv = t >> 6;       // wv 0..7
  int q = lane >> 4, n = lane & 15;

  float aNext = (sel < 2) ? AF[g * 2 + sel] : 0.f;
  float invA  = (sel > 0) ? 1.0f / AF[g * 2 + sel - 1] : 0.f;

  // staging invariants
  int scol = t & 127;
  int shalf = (t >> 7) & 1;
  int srow0 = t >> 8;                   // 0 or 1

  // ---- static zero region: halo cols 0/129; sel0 half==1 plane; OOB rows ----
  {
    uint4v z = (uint4v){0u, 0u, 0u, 0u};
    int zmax = (sel == 0) ? 1320 : 40;
    for (int i = t; i < zmax; i += 512) {
      int row, half, col;
      if (i < 40) { row = i >> 2; half = (i >> 1) & 1; col = (i & 1) ? 129 : 0; }
      else { int j = i - 40; row = j >> 7; col = (j & 127) + 1; half = 1; }
      *(uint4v*)((char*)s_lds + (size_t)(((row * 2 + half) * 132 + col)) * 16) = z;
    }
    // OOB rows (edge blocks only): grow = row0-1+row outside [0,128)
    for (int row = 0; row < 10; row++) {
      int grow = row0 - 1 + row;
      if ((unsigned)grow >= 128u) {
        for (int i = t; i < 264; i += 512) {
          int half = i / 132, col = i % 132;
          *(uint4v*)((char*)s_lds + (size_t)((row * 2 + half) * 132 + col) * 16) = z;
        }
      }
    }
  }

  // per-lane B-read offsets (bytes) for the 5 K-steps of a dz phase
  int basel = wv * 4224 + (q & 1) * 2112 + n * 16;
  int off2[5];
#pragma unroll
  for (int i = 0; i < 5; i++) {
    int tl = 2 * i + (q >> 1);
    if (tl > 8) tl = 8;
    int ky = tl / 3, kx = tl % 3;
    off2[i] = basel + ky * 4224 + kx * 16;
  }

  int setIdx = (sel == 0) ? g : (4 + g * 2 + (sel - 1));
  const char* WsetBase = (const char*)Wmf + (size_t)setIdx * 15 * 1024;

  floatx4 acc[8];
#pragma unroll
  for (int cg = 0; cg < 8; cg++) acc[cg] = (floatx4){0.f, 0.f, 0.f, 0.f};

  for (int d = 0; d < 3; d++) {
    int l2 = l + d - 1;
    if (l2 < 0 || l2 >= Ls) continue;     // block-uniform
    int p2 = p + d - 1;
    __syncthreads();
    // ---- stage slab interior ----
    if (sel == 0) {
      if (shalf == 0) {
#pragma unroll
        for (int it = 0; it < 5; it++) {
          int row = srow0 + it * 2;
          int grow = row0 - 1 + row;
          if ((unsigned)grow < 128u) {
            uint2v v2 = *(const uint2v*)(src + ((size_t)p2 * HW + grow * 128 + scol) * 4);
            uint4v val; val.x = v2.x; val.y = v2.y; val.z = 0u; val.w = 0u;
            *(uint4v*)((char*)s_lds + (size_t)((row * 2) * 132 + scol + 1) * 16) = val;
          }
        }
      }
    } else {
#pragma unroll
      for (int it = 0; it < 5; it++) {
        int row = srow0 + it * 2;
        int grow = row0 - 1 + row;
        if ((unsigned)grow < 128u) {      // wave-uniform
          const void* gp = (const void*)(src +
              (((size_t)p2 * HW + (size_t)grow * 128 + scol) * 16 + shalf * 8));
          void* lp = (void*)((char*)s_lds +
              (size_t)((row * 2 + shalf) * 132 + (wv & 1) * 64 + 1) * 16);
          gl_lds16(gp, lp);
        }
      }
    }
    __syncthreads();
    // ---- A fragments + MFMA ----
    short8 af[5];
#pragma unroll
    for (int i = 0; i < 5; i++)
      af[i] = *(const short8*)(WsetBase + ((d * 5 + i) * 64 + lane) * 16);
#pragma unroll
    for (int cg = 0; cg < 8; cg++) {
#pragma unroll
      for (int i = 0; i < 5; i++) {
        short8 b = *(const short8*)((const char*)s_lds + off2[i] + cg * 256);
        acc[cg] = __builtin_amdgcn_mfma_f32_16x16x32_bf16(af[i], b, acc[cg], 0, 0, 0);
      }
    }
  }

  // ---- epilogue ----
  const float* bp = (sel == 0) ? (BiF + g * 16) : (BbF + g * 32 + (sel - 1) * 16);
  float bz[4];
#pragma unroll
  for (int r = 0; r < 4; r++) bz[r] = bp[q * 4 + r];
  int h = row0 + wv;

  if (sel < 2) {
#pragma unroll
    for (int cg = 0; cg < 8; cg++) {
      size_t pix = (size_t)p * HW + h * 128 + cg * 16 + n;
      float r0 = acc[cg][0] + bz[0], r1 = acc[cg][1] + bz[1];
      float r2 = acc[cg][2] + bz[2], r3 = acc[cg][3] + bz[3];
      if (sel != 0) {
        uint2v pv = *(const uint2v*)(prevAct + pix * 16 + q * 4);
        r0 += invprelu(bflo(pv.x), invA); r1 += invprelu(bfhi(pv.x), invA);
        r2 += invprelu(bflo(pv.y), invA); r3 += invprelu(bfhi(pv.y), invA);
      }
      // store activated with consumer's alpha
      r0 = fmaxf(r0, 0.f) + aNext * fminf(r0, 0.f);
      r1 = fmaxf(r1, 0.f) + aNext * fminf(r1, 0.f);
      r2 = fmaxf(r2, 0.f) + aNext * fminf(r2, 0.f);
      r3 = fmaxf(r3, 0.f) + aNext * fminf(r3, 0.f);
      uint2v ov; ov.x = pack2(r0, r1); ov.y = pack2(r2, r3);
      *(uint2v*)(boutAct + pix * 16 + q * 4) = ov;
    }
  } else {
    // fused (raw0 + y2) 1x1 w_last -> xrb[p][c][hw]
    float invA0 = 1.0f / AF[g * 2];
    float wl0[4], wl1[4], wl2[4];
#pragma unroll
    for (int r = 0; r < 4; r++) {
      wl0[r] = WlF[q * 4 + r];
      wl1[r] = WlF[16 + q * 4 + r];
      wl2[r] = WlF[32 + q * 4 + r];
    }
#pragma unroll
    for (int cg = 0; cg < 8; cg++) {
      size_t pix = (size_t)p * HW + h * 128 + cg * 16 + n;
      float r0 = acc[cg][0] + bz[0], r1 = acc[cg][1] + bz[1];
      float r2 = acc[cg][2] + bz[2], r3 = acc[cg][3] + bz[3];
      uint2v pv = *(const uint2v*)(prevAct + pix * 16 + q * 4);
      r0 += invprelu(bflo(pv.x), invA); r1 += invprelu(bfhi(pv.x), invA);
      r2 += invprelu(bflo(pv.y), invA); r3 += invprelu(bfhi(pv.y), invA);
      uint2v p0 = *(const uint2v*)(act0 + pix * 16 + q * 4);
      r0 += invprelu(bflo(p0.x), invA0); r1 += invprelu(bfhi(p0.x), invA0);
      r2 += invprelu(bflo(p0.y), invA0); r3 += invprelu(bfhi(p0.y), invA0);
      float o0 = wl0[0] * r0 + wl0[1] * r1 + wl0[2] * r2 + wl0[3] * r3;
      float o1 = wl1[0] * r0 + wl1[1] * r1 + wl1[2] * r2 + wl1[3] * r3;
      float o2 = wl2[0] * r0 + wl2[1] * r1 + wl2[2] * r2 + wl2[3] * r3;
      o0 += __shfl_xor(o0, 16); o0 += __shfl_xor(o0, 32);
      o1 += __shfl_xor(o1, 16); o1 += __shfl_xor(o1, 32);
      o2 += __shfl_xor(o2, 16); o2 += __shfl_xor(o2, 32);
      if (q == 0) {
        size_t hw = (size_t)h * 128 + cg * 16 + n;
        xrbOut[((size_t)p * 3 + 0) * HW + hw] = o0;
        xrbOut[((size_t)p * 3 + 1) * HW + hw] = o1;
        xrbOut[((size_t)p * 3 + 2) * HW + hw] = o2;
      }
    }
  }
}

extern "C" void kernel_launch(void* const* d_in, const int* in_sizes, int n_in,
                              void* d_out, int out_size, void* d_ws, size_t ws_size,
                              hipStream_t stream) {
  (void)in_sizes; (void)n_in; (void)out_size; (void)ws_size;
  const float* x = (const float*)d_in[0];
  WPtrs P;
  for (int g = 0; g < 4; g++) {
    int b = 1 + g * 5;
    P.wi[g] = (const float*)d_in[b + 0];
    P.bi[g] = (const float*)d_in[b + 1];
    P.a[g]  = (const float*)d_in[b + 2];
    P.wb[g] = (const float*)d_in[b + 3];
    P.bb[g] = (const float*)d_in[b + 4];
  }
  P.wl = (const float*)d_in[21];

  char* base = (char*)d_ws;
  size_t off = 0;
  auto take = [&](size_t bytes) -> char* {
    char* r = base + off;
    off += (bytes + 255) & ~(size_t)255;
    return r;
  };
  float* DaF = (float*)take(81 * 4);
  unsigned short* TFhi = (unsigned short*)take(16384 * 2);
  unsigned short* TFlo = (unsigned short*)take(16384 * 2);
  unsigned short* TIhi = (unsigned short*)take(16384 * 2);
  unsigned short* TIlo = (unsigned short*)take(16384 * 2);
  unsigned short* Wmf = (unsigned short*)take(92160 * 2);
  float* BiF   = (float*)take(256);
  float* BbF   = (float*)take(512);
  float* AF    = (float*)take(32);
  float* WlF   = (float*)take(192);
  float* R1 = (float*)take((size_t)NSLICE * HW * 4);   // dct2-fwd out | angI out
  float* R3 = (float*)take((size_t)NSLICE * HW * 4);   // xf2b (bf16) | xrb (f32)
  unsigned short* braw0 = (unsigned short*)take((size_t)81 * 16 * HW * 2);
  unsigned short* braw1 = (unsigned short*)take((size_t)81 * 16 * HW * 2);
  unsigned short* xf2b = (unsigned short*)R3;          // 10.6 MB < 15.9 MB
  float* xrb = R3;

  k_setup<<<64, 256, 0, stream>>>(DaF, TFhi, TFlo, TIhi, TIlo);
  k_prep<<<360, 256, 0, stream>>>(P, Wmf, BiF, BbF, AF, WlF);
  // fused forward spatial DCT (per-slice MFMA split-bf16)
  k_dct2<<<243, 256, 0, stream>>>(x, TFhi, TFlo, nullptr, R1);
  // fused forward angular DCT (both passes) + band gather -> channels-last bf16
  k_angF<<<dim3(128, 3), 128, 0, stream>>>(R1, DaF, xf2b);
  // branch convs (MFMA implicit GEMM; act-forwarding; sel2 fuses 1x1 epi)
  k_conv<<<dim3(16, 81), 512, 0, stream>>>(xf2b, nullptr, nullptr, Wmf,
                                           BiF, BbF, AF, WlF, 0, braw0, nullptr);
  k_conv<<<dim3(16, 81), 512, 0, stream>>>(braw0, braw0, nullptr, Wmf,
                                           BiF, BbF, AF, WlF, 1, braw1, nullptr);
  k_conv<<<dim3(16, 81), 512, 0, stream>>>(braw1, braw1, braw0, Wmf,
                                           BiF, BbF, AF, WlF, 2, nullptr, xrb);
  // fused inverse angular DCT (band scatter in load)
  k_angI<<<dim3(128, 3), 128, 0, stream>>>(xrb, DaF, R1);
  // fused inverse spatial DCT + residual add
  k_dct2<<<243, 256, 0, stream>>>(R1, TIhi, TIlo, x, (float*)d_out);
}

// Round 8
// 290.285 us; speedup vs baseline: 1.0393x; 1.0393x over previous
//
#include <hip/hip_runtime.h>
#include <hip/hip_bf16.h>
#include <math.h>

typedef __hip_bfloat16 bf16;
typedef __attribute__((ext_vector_type(8))) short short8;
typedef __attribute__((ext_vector_type(4))) float floatx4;
typedef __attribute__((ext_vector_type(4))) unsigned int uint4v;
typedef __attribute__((ext_vector_type(2))) unsigned int uint2v;

#define HW 16384          // 128*128
#define NSLICE 243        // 9*9*3

// ---- band tables (anti-diagonals of 9x9 grid) ----
__constant__ int c_s_of_p[81] = {
  0, 1,1, 2,2,2, 3,3,3,3, 4,4,4,4,4, 5,5,5,5,5,5, 6,6,6,6,6,6,6,
  7,7,7,7,7,7,7,7, 8,8,8,8,8,8,8,8,8, 9,9,9,9,9,9,9,9,
  10,10,10,10,10,10,10, 11,11,11,11,11,11, 12,12,12,12,12,
  13,13,13,13, 14,14,14, 15,15, 16};
__constant__ int c_l_of_p[81] = {
  0, 0,1, 0,1,2, 0,1,2,3, 0,1,2,3,4, 0,1,2,3,4,5, 0,1,2,3,4,5,6,
  0,1,2,3,4,5,6,7, 0,1,2,3,4,5,6,7,8, 0,1,2,3,4,5,6,7,
  0,1,2,3,4,5,6, 0,1,2,3,4,5, 0,1,2,3,4, 0,1,2,3, 0,1,2, 0,1, 0};
__constant__ int c_L_of_s[17] = {1,2,3,4,5,6,7,8,9,8,7,6,5,4,3,2,1};
__constant__ int c_g_of_s[17] = {0,1,1,2,2,2,2,2,2,3,3,3,3,3,3,3,3};
__constant__ int c_pos_uv[81] = {
  0,1,3,6,10,15,21,28,36,
  2,4,7,11,16,22,29,37,45,
  5,8,12,17,23,30,38,46,53,
  9,13,18,24,31,39,47,54,60,
  14,19,25,32,40,48,55,61,66,
  20,26,33,41,49,56,62,67,71,
  27,34,42,50,57,63,68,72,75,
  35,43,51,58,64,69,73,76,78,
  44,52,59,65,70,74,77,79,80};

struct WPtrs {
  const float* wi[4]; const float* bi[4]; const float* a[4];
  const float* wb[4]; const float* bb[4]; const float* wl;
};

__device__ __forceinline__ unsigned short f2bf(float f) {
  return __bfloat16_as_ushort(__float2bfloat16(f));
}
__device__ __forceinline__ float bf2f(unsigned short u) {
  return __uint_as_float(((unsigned int)u) << 16);
}
__device__ __forceinline__ float bflo(unsigned int w) {
  return __uint_as_float(w << 16);
}
__device__ __forceinline__ float bfhi(unsigned int w) {
  return __uint_as_float(w & 0xffff0000u);
}
__device__ __forceinline__ unsigned int pack2(float a, float b) {
  return (unsigned int)f2bf(a) | ((unsigned int)f2bf(b) << 16);
}
// inverse PReLU: raw = v>=0 ? v : v*invA  (exact for alpha = power of two)
__device__ __forceinline__ float invprelu(float v, float invA) {
  return (v >= 0.f) ? v : v * invA;
}
// split fp32 into bf16 hi (truncate) + bf16 lo (RNE of remainder): ~2^-17 rel
__device__ __forceinline__ void bfsplit(float v, unsigned short& hi, unsigned short& lo) {
  unsigned int bits = __float_as_uint(v);
  hi = (unsigned short)(bits >> 16);
  lo = f2bf(v - __uint_as_float(bits & 0xffff0000u));
}
// async global->LDS 16B: LDS dest = wave-uniform base + lane*16
__device__ __forceinline__ void gl_lds16(const void* g, void* l) {
  __builtin_amdgcn_global_load_lds(
      (const __attribute__((address_space(1))) unsigned int*)g,
      (__attribute__((address_space(3))) unsigned int*)l, 16, 0, 0);
}
// conv LDS plane layout with bank-phase swizzle: plane stride 2112 B, plus
// (plane&3)*32 B so consecutive planes land on phases {0,96,64,32} mod 128 B.
__device__ __forceinline__ int ldsoff(int plane, int col) {
  return plane * 2112 + ((plane & 3) << 5) + (col << 4);
}

// ---- merged setup: DCT tables + conv weight repack (one dispatch) ----
__global__ __launch_bounds__(256) void k_init(WPtrs P, float* DaF,
                                              unsigned short* TFhi, unsigned short* TFlo,
                                              unsigned short* TIhi, unsigned short* TIlo,
                                              unsigned short* Wmf,
                                              float* BiF, float* BbF,
                                              float* AF, float* WlF) {
  const double PI = 3.14159265358979323846;
  int t = blockIdx.x * 256 + threadIdx.x;
  if (t < 81) {   // Da[U][u]
    int U = t / 9, u = t % 9;
    double d = cos(PI * (u + 0.5) * U / 9.0) * sqrt(2.0 / 9.0);
    if (U == 0) d *= (1.0 / sqrt(2.0));
    DaF[t] = (float)d;
  }
  if (t < 16384) {
    int jj = t & 7, lane = (t >> 3) & 63, ks = (t >> 9) & 3, tile = t >> 11;
    int row = tile * 16 + (lane & 15);
    int colk = ks * 32 + (lane >> 4) * 8 + jj;
    double vF = cos(PI * (colk + 0.5) * row / 128.0) * sqrt(2.0 / 128.0);
    if (row == 0) vF *= (1.0 / sqrt(2.0));
    double vI = cos(PI * (row + 0.5) * colk / 128.0) * sqrt(2.0 / 128.0);
    if (colk == 0) vI *= (1.0 / sqrt(2.0));
    unsigned short h, l;
    bfsplit((float)vF, h, l); TFhi[t] = h; TFlo[t] = l;
    bfsplit((float)vI, h, l); TIhi[t] = h; TIlo[t] = l;
  }
  if (t < 92160) {
    int s = t / 7680, r = t % 7680;
    int step = r / 512, r2 = r % 512;
    int lane = r2 >> 3, j = r2 & 7;
    int d = step / 5, i = step % 5;
    int q = lane >> 4, m = lane & 15;
    int tl = 2 * i + (q >> 1);
    int cin = (q & 1) * 8 + j;
    float val = 0.f;
    if (tl <= 8) {
      int ky = tl / 3, kx = tl % 3;
      int tap = d * 9 + ky * 3 + kx;
      if (s < 4) {
        if (cin < 3) val = P.wi[s][(m * 3 + cin) * 27 + tap];
      } else {
        int g = (s - 4) >> 1, k = (s - 4) & 1;
        val = P.wb[g][((k * 16 + m) * 16 + cin) * 27 + tap];
      }
    }
    Wmf[t] = f2bf(val);
  }
  if (t < 64)  BiF[t] = P.bi[t / 16][t % 16];
  if (t < 128) BbF[t] = P.bb[t / 32][t % 32];
  if (t < 8)   AF[t]  = P.a[t / 2][t % 2];
  if (t < 48)  WlF[t] = P.wl[t];
}

// ---- fused spatial DCT: Y = Dop * X * Dop^T per 128x128 slice ----
// Ybf != null: write bf16 (forward path). Else write f32 (+ optional residual).
__global__ __launch_bounds__(256) void k_dct2(const float* __restrict__ X,
                                              const unsigned short* __restrict__ tabhi,
                                              const unsigned short* __restrict__ tablo,
                                              const float* __restrict__ xres,
                                              float* __restrict__ Yf,
                                              unsigned short* __restrict__ Ybf) {
  __shared__ unsigned short sThi[128 * 136];
  __shared__ unsigned short sTlo[128 * 136];
  int s = blockIdx.x;
  int t = threadIdx.x;
  int lane = t & 63, wv = t >> 6;
  int q = lane >> 4, n16 = lane & 15;
  const float* Xs = X + (size_t)s * HW;

  floatx4 acc[2][8];
#pragma unroll
  for (int mt = 0; mt < 2; mt++)
#pragma unroll
    for (int nt = 0; nt < 8; nt++) acc[mt][nt] = (floatx4){0.f, 0.f, 0.f, 0.f};

#pragma unroll
  for (int ks = 0; ks < 4; ks++) {
    short8 ahi[2], alo[2];
#pragma unroll
    for (int mt = 0; mt < 2; mt++) {
      const float* xp = Xs + (wv * 32 + mt * 16 + n16) * 128 + ks * 32 + q * 8;
      float4 a = *(const float4*)xp;
      float4 b = *(const float4*)(xp + 4);
      union { short8 v; unsigned short u[8]; } H, L;
      float xv[8] = {a.x, a.y, a.z, a.w, b.x, b.y, b.z, b.w};
#pragma unroll
      for (int j = 0; j < 8; j++) bfsplit(xv[j], H.u[j], L.u[j]);
      ahi[mt] = H.v; alo[mt] = L.v;
    }
#pragma unroll
    for (int nt = 0; nt < 8; nt++) {
      int e = nt * 2048 + ks * 512 + lane * 8;
      short8 bh = *(const short8*)(tabhi + e);
      short8 bl = *(const short8*)(tablo + e);
#pragma unroll
      for (int mt = 0; mt < 2; mt++) {
        acc[mt][nt] = __builtin_amdgcn_mfma_f32_16x16x32_bf16(ahi[mt], bl, acc[mt][nt], 0, 0, 0);
        acc[mt][nt] = __builtin_amdgcn_mfma_f32_16x16x32_bf16(alo[mt], bh, acc[mt][nt], 0, 0, 0);
        acc[mt][nt] = __builtin_amdgcn_mfma_f32_16x16x32_bf16(ahi[mt], bh, acc[mt][nt], 0, 0, 0);
      }
    }
  }

#pragma unroll
  for (int mt = 0; mt < 2; mt++)
#pragma unroll
    for (int nt = 0; nt < 8; nt++) {
      int col = nt * 16 + n16;
      int rowb = wv * 32 + mt * 16 + q * 4;
#pragma unroll
      for (int rp = 0; rp < 4; rp += 2) {
        unsigned short h0, l0, h1, l1;
        bfsplit(acc[mt][nt][rp], h0, l0);
        bfsplit(acc[mt][nt][rp + 1], h1, l1);
        int widx = (col * 136 + rowb + rp) >> 1;
        ((unsigned int*)sThi)[widx] = (unsigned int)h0 | ((unsigned int)h1 << 16);
        ((unsigned int*)sTlo)[widx] = (unsigned int)l0 | ((unsigned int)l1 << 16);
      }
    }
  __syncthreads();

#pragma unroll
  for (int mt = 0; mt < 2; mt++)
#pragma unroll
    for (int nt = 0; nt < 8; nt++) acc[mt][nt] = (floatx4){0.f, 0.f, 0.f, 0.f};

#pragma unroll
  for (int ks = 0; ks < 4; ks++) {
    short8 ahi[2], alo[2];
#pragma unroll
    for (int mt = 0; mt < 2; mt++) {
      int e = (wv * 2 + mt) * 2048 + ks * 512 + lane * 8;
      ahi[mt] = *(const short8*)(tabhi + e);
      alo[mt] = *(const short8*)(tablo + e);
    }
#pragma unroll
    for (int nt = 0; nt < 8; nt++) {
      int off = (nt * 16 + n16) * 136 + ks * 32 + q * 8;
      short8 bh = *(const short8*)(sThi + off);
      short8 bl = *(const short8*)(sTlo + off);
#pragma unroll
      for (int mt = 0; mt < 2; mt++) {
        acc[mt][nt] = __builtin_amdgcn_mfma_f32_16x16x32_bf16(ahi[mt], bl, acc[mt][nt], 0, 0, 0);
        acc[mt][nt] = __builtin_amdgcn_mfma_f32_16x16x32_bf16(alo[mt], bh, acc[mt][nt], 0, 0, 0);
        acc[mt][nt] = __builtin_amdgcn_mfma_f32_16x16x32_bf16(ahi[mt], bh, acc[mt][nt], 0, 0, 0);
      }
    }
  }

#pragma unroll
  for (int mt = 0; mt < 2; mt++)
#pragma unroll
    for (int nt = 0; nt < 8; nt++) {
      int row0 = wv * 32 + mt * 16 + q * 4;
      int col = nt * 16 + n16;
#pragma unroll
      for (int r = 0; r < 4; r++) {
        size_t oi = (size_t)s * HW + (size_t)(row0 + r) * 128 + col;
        float v = acc[mt][nt][r];
        if (Ybf) {
          Ybf[oi] = f2bf(v);
        } else {
          if (xres) v += xres[oi];
          Yf[oi] = v;
        }
      }
    }
}

// ---- separable angular DCT (streaming, 9-value state, bf16 intermediates) ----
// fwd pass 1 (along u): bf16 in -> bf16 out
__global__ __launch_bounds__(256) void k_angu(const unsigned short* __restrict__ in,
                                              const float* __restrict__ DaF,
                                              unsigned short* __restrict__ out) {
  __shared__ float sDa[81];
  int t = threadIdx.x;
  if (t < 81) sDa[t] = DaF[t];
  __syncthreads();
  int idx = blockIdx.x * 256 + t;   // 27*HW
  int hw = idx & (HW - 1);
  int r = idx >> 14;
  int c = r % 3, v = r / 3;
  float f[9];
#pragma unroll
  for (int u = 0; u < 9; u++) f[u] = bf2f(in[(size_t)((u * 9 + v) * 3 + c) * HW + hw]);
#pragma unroll
  for (int U = 0; U < 9; U++) {
    float acc = 0.f;
#pragma unroll
    for (int u = 0; u < 9; u++) acc += sDa[U * 9 + u] * f[u];
    out[(size_t)((U * 9 + v) * 3 + c) * HW + hw] = f2bf(acc);
  }
}

// fwd pass 2 (along v) + band gather + bf16 pack (channels-last padded-4)
__global__ __launch_bounds__(256) void k_angv(const unsigned short* __restrict__ in,
                                              const float* __restrict__ DaF,
                                              unsigned short* __restrict__ xf2b) {
  __shared__ float sDa[81];
  int t = threadIdx.x;
  if (t < 81) sDa[t] = DaF[t];
  __syncthreads();
  int idx = blockIdx.x * 256 + t;
  int hw = idx & (HW - 1);
  int r = idx >> 14;
  int c = r % 3, U = r / 3;
  float f[9];
#pragma unroll
  for (int v = 0; v < 9; v++) f[v] = bf2f(in[(size_t)((U * 9 + v) * 3 + c) * HW + hw]);
#pragma unroll
  for (int V = 0; V < 9; V++) {
    float acc = 0.f;
#pragma unroll
    for (int v = 0; v < 9; v++) acc += sDa[V * 9 + v] * f[v];
    size_t base = ((size_t)c_pos_uv[U * 9 + V] * HW + hw) * 4;
    xf2b[base + c] = f2bf(acc);
    if (c == 0) xf2b[base + 3] = 0;
  }
}

// inv pass 1 (along V) + band scatter read: f32 xrb -> bf16 tmp
__global__ __launch_bounds__(256) void k_angvi(const float* __restrict__ xrb,
                                               const float* __restrict__ DaF,
                                               unsigned short* __restrict__ out) {
  __shared__ float sDa[81];
  int t = threadIdx.x;
  if (t < 81) sDa[t] = DaF[t];
  __syncthreads();
  int idx = blockIdx.x * 256 + t;
  int hw = idx & (HW - 1);
  int r = idx >> 14;
  int c = r % 3, U = r / 3;
  float f[9];
#pragma unroll
  for (int V = 0; V < 9; V++)
    f[V] = xrb[((size_t)c_pos_uv[U * 9 + V] * 3 + c) * HW + hw];
#pragma unroll
  for (int v = 0; v < 9; v++) {
    float acc = 0.f;
#pragma unroll
    for (int V = 0; V < 9; V++) acc += sDa[V * 9 + v] * f[V];
    out[(size_t)((U * 9 + v) * 3 + c) * HW + hw] = f2bf(acc);
  }
}

// inv pass 2 (along U): bf16 tmp -> f32 (dct2-inv input precision kept f32)
__global__ __launch_bounds__(256) void k_angui(const unsigned short* __restrict__ in,
                                               const float* __restrict__ DaF,
                                               float* __restrict__ out) {
  __shared__ float sDa[81];
  int t = threadIdx.x;
  if (t < 81) sDa[t] = DaF[t];
  __syncthreads();
  int idx = blockIdx.x * 256 + t;
  int hw = idx & (HW - 1);
  int r = idx >> 14;
  int c = r % 3, v = r / 3;
  float f[9];
#pragma unroll
  for (int U = 0; U < 9; U++) f[U] = bf2f(in[(size_t)((U * 9 + v) * 3 + c) * HW + hw]);
#pragma unroll
  for (int u = 0; u < 9; u++) {
    float acc = 0.f;
#pragma unroll
    for (int U = 0; U < 9; U++) acc += sDa[U * 9 + u] * f[U];
    out[(size_t)((u * 9 + v) * 3 + c) * HW + hw] = acc;
  }
}

// ---- MFMA implicit-GEMM 3x3x3 conv, 8 output rows per 512-thread block ----
// Async global->LDS staging; LDS plane layout bank-phase swizzled (ldsoff).
__global__ __launch_bounds__(512) void k_conv(const unsigned short* __restrict__ src,
                                              const unsigned short* __restrict__ prevAct,
                                              const unsigned short* __restrict__ act0,
                                              const unsigned short* __restrict__ Wmf,
                                              const float* __restrict__ BiF,
                                              const float* __restrict__ BbF,
                                              const float* __restrict__ AF,
                                              const float* __restrict__ WlF,
                                              int sel,
                                              unsigned short* __restrict__ boutAct,
                                              float* __restrict__ xrbOut) {
  __shared__ unsigned short s_lds[21184];   // 42368 B (swizzled planes)
  int p = blockIdx.y;
  int s = c_s_of_p[p], l = c_l_of_p[p];
  int g = c_g_of_s[s], Ls = c_L_of_s[s];
  int row0 = blockIdx.x * 8;
  int t = threadIdx.x;
  int lane = t & 63, wv = t >> 6;       // wv 0..7
  int q = lane >> 4, n = lane & 15;

  float aNext = (sel < 2) ? AF[g * 2 + sel] : 0.f;
  float invA  = (sel > 0) ? 1.0f / AF[g * 2 + sel - 1] : 0.f;

  // staging invariants
  int scol = t & 127;
  int shalf = (t >> 7) & 1;
  int srow0 = t >> 8;                   // 0 or 1

  // ---- static zero region: halo cols 0/129; sel0 half==1 plane; OOB rows ----
  {
    uint4v z = (uint4v){0u, 0u, 0u, 0u};
    int zmax = (sel == 0) ? 1320 : 40;
    for (int i = t; i < zmax; i += 512) {
      int row, half, col;
      if (i < 40) { row = i >> 2; half = (i >> 1) & 1; col = (i & 1) ? 129 : 0; }
      else { int j = i - 40; row = j >> 7; col = (j & 127) + 1; half = 1; }
      *(uint4v*)((char*)s_lds + ldsoff(row * 2 + half, col)) = z;
    }
    // OOB rows (edge blocks only)
    for (int row = 0; row < 10; row++) {
      int grow = row0 - 1 + row;
      if ((unsigned)grow >= 128u) {
        for (int i = t; i < 264; i += 512) {
          int half = i / 132, col = i % 132;
          *(uint4v*)((char*)s_lds + ldsoff(row * 2 + half, col)) = z;
        }
      }
    }
  }

  // per-lane B-read offsets (bytes) for the 5 K-steps of a dz phase
  int off2[5];
#pragma unroll
  for (int i = 0; i < 5; i++) {
    int tl = 2 * i + (q >> 1);
    if (tl > 8) tl = 8;
    int ky = tl / 3, kx = tl % 3;
    off2[i] = ldsoff(2 * (wv + ky) + (q & 1), n + kx);
  }

  int setIdx = (sel == 0) ? g : (4 + g * 2 + (sel - 1));
  const char* WsetBase = (const char*)Wmf + (size_t)setIdx * 15 * 1024;

  floatx4 acc[8];
#pragma unroll
  for (int cg = 0; cg < 8; cg++) acc[cg] = (floatx4){0.f, 0.f, 0.f, 0.f};

  for (int d = 0; d < 3; d++) {
    int l2 = l + d - 1;
    if (l2 < 0 || l2 >= Ls) continue;     // block-uniform
    int p2 = p + d - 1;
    __syncthreads();
    // ---- stage slab interior ----
    if (sel == 0) {
      if (shalf == 0) {
#pragma unroll
        for (int it = 0; it < 5; it++) {
          int row = srow0 + it * 2;
          int grow = row0 - 1 + row;
          if ((unsigned)grow < 128u) {
            uint2v v2 = *(const uint2v*)(src + ((size_t)p2 * HW + grow * 128 + scol) * 4);
            uint4v val; val.x = v2.x; val.y = v2.y; val.z = 0u; val.w = 0u;
            *(uint4v*)((char*)s_lds + ldsoff(row * 2, scol + 1)) = val;
          }
        }
      }
    } else {
#pragma unroll
      for (int it = 0; it < 5; it++) {
        int row = srow0 + it * 2;
        int grow = row0 - 1 + row;
        if ((unsigned)grow < 128u) {      // wave-uniform
          const void* gp = (const void*)(src +
              (((size_t)p2 * HW + (size_t)grow * 128 + scol) * 16 + shalf * 8));
          void* lp = (void*)((char*)s_lds +
              ldsoff(row * 2 + shalf, (wv & 1) * 64 + 1));
          gl_lds16(gp, lp);
        }
      }
    }
    __syncthreads();
    // ---- A fragments + MFMA ----
    short8 af[5];
#pragma unroll
    for (int i = 0; i < 5; i++)
      af[i] = *(const short8*)(WsetBase + ((d * 5 + i) * 64 + lane) * 16);
#pragma unroll
    for (int cg = 0; cg < 8; cg++) {
#pragma unroll
      for (int i = 0; i < 5; i++) {
        short8 b = *(const short8*)((const char*)s_lds + off2[i] + cg * 256);
        acc[cg] = __builtin_amdgcn_mfma_f32_16x16x32_bf16(af[i], b, acc[cg], 0, 0, 0);
      }
    }
  }

  // ---- epilogue ----
  const float* bp = (sel == 0) ? (BiF + g * 16) : (BbF + g * 32 + (sel - 1) * 16);
  float bz[4];
#pragma unroll
  for (int r = 0; r < 4; r++) bz[r] = bp[q * 4 + r];
  int h = row0 + wv;

  if (sel < 2) {
#pragma unroll
    for (int cg = 0; cg < 8; cg++) {
      size_t pix = (size_t)p * HW + h * 128 + cg * 16 + n;
      float r0 = acc[cg][0] + bz[0], r1 = acc[cg][1] + bz[1];
      float r2 = acc[cg][2] + bz[2], r3 = acc[cg][3] + bz[3];
      if (sel != 0) {
        uint2v pv = *(const uint2v*)(prevAct + pix * 16 + q * 4);
        r0 += invprelu(bflo(pv.x), invA); r1 += invprelu(bfhi(pv.x), invA);
        r2 += invprelu(bflo(pv.y), invA); r3 += invprelu(bfhi(pv.y), invA);
      }
      // store activated with consumer's alpha
      r0 = fmaxf(r0, 0.f) + aNext * fminf(r0, 0.f);
      r1 = fmaxf(r1, 0.f) + aNext * fminf(r1, 0.f);
      r2 = fmaxf(r2, 0.f) + aNext * fminf(r2, 0.f);
      r3 = fmaxf(r3, 0.f) + aNext * fminf(r3, 0.f);
      uint2v ov; ov.x = pack2(r0, r1); ov.y = pack2(r2, r3);
      *(uint2v*)(boutAct + pix * 16 + q * 4) = ov;
    }
  } else {
    // fused (raw0 + y2) 1x1 w_last -> xrb[p][c][hw]
    float invA0 = 1.0f / AF[g * 2];
    float wl0[4], wl1[4], wl2[4];
#pragma unroll
    for (int r = 0; r < 4; r++) {
      wl0[r] = WlF[q * 4 + r];
      wl1[r] = WlF[16 + q * 4 + r];
      wl2[r] = WlF[32 + q * 4 + r];
    }
#pragma unroll
    for (int cg = 0; cg < 8; cg++) {
      size_t pix = (size_t)p * HW + h * 128 + cg * 16 + n;
      float r0 = acc[cg][0] + bz[0], r1 = acc[cg][1] + bz[1];
      float r2 = acc[cg][2] + bz[2], r3 = acc[cg][3] + bz[3];
      uint2v pv = *(const uint2v*)(prevAct + pix * 16 + q * 4);
      r0 += invprelu(bflo(pv.x), invA); r1 += invprelu(bfhi(pv.x), invA);
      r2 += invprelu(bflo(pv.y), invA); r3 += invprelu(bfhi(pv.y), invA);
      uint2v p0 = *(const uint2v*)(act0 + pix * 16 + q * 4);
      r0 += invprelu(bflo(p0.x), invA0); r1 += invprelu(bfhi(p0.x), invA0);
      r2 += invprelu(bflo(p0.y), invA0); r3 += invprelu(bfhi(p0.y), invA0);
      float o0 = wl0[0] * r0 + wl0[1] * r1 + wl0[2] * r2 + wl0[3] * r3;
      float o1 = wl1[0] * r0 + wl1[1] * r1 + wl1[2] * r2 + wl1[3] * r3;
      float o2 = wl2[0] * r0 + wl2[1] * r1 + wl2[2] * r2 + wl2[3] * r3;
      o0 += __shfl_xor(o0, 16); o0 += __shfl_xor(o0, 32);
      o1 += __shfl_xor(o1, 16); o1 += __shfl_xor(o1, 32);
      o2 += __shfl_xor(o2, 16); o2 += __shfl_xor(o2, 32);
      if (q == 0) {
        size_t hw = (size_t)h * 128 + cg * 16 + n;
        xrbOut[((size_t)p * 3 + 0) * HW + hw] = o0;
        xrbOut[((size_t)p * 3 + 1) * HW + hw] = o1;
        xrbOut[((size_t)p * 3 + 2) * HW + hw] = o2;
      }
    }
  }
}

extern "C" void kernel_launch(void* const* d_in, const int* in_sizes, int n_in,
                              void* d_out, int out_size, void* d_ws, size_t ws_size,
                              hipStream_t stream) {
  (void)in_sizes; (void)n_in; (void)out_size; (void)ws_size;
  const float* x = (const float*)d_in[0];
  WPtrs P;
  for (int g = 0; g < 4; g++) {
    int b = 1 + g * 5;
    P.wi[g] = (const float*)d_in[b + 0];
    P.bi[g] = (const float*)d_in[b + 1];
    P.a[g]  = (const float*)d_in[b + 2];
    P.wb[g] = (const float*)d_in[b + 3];
    P.bb[g] = (const float*)d_in[b + 4];
  }
  P.wl = (const float*)d_in[21];

  char* base = (char*)d_ws;
  size_t off = 0;
  auto take = [&](size_t bytes) -> char* {
    char* r = base + off;
    off += (bytes + 255) & ~(size_t)255;
    return r;
  };
  float* DaF = (float*)take(81 * 4);
  unsigned short* TFhi = (unsigned short*)take(16384 * 2);
  unsigned short* TFlo = (unsigned short*)take(16384 * 2);
  unsigned short* TIhi = (unsigned short*)take(16384 * 2);
  unsigned short* TIlo = (unsigned short*)take(16384 * 2);
  unsigned short* Wmf = (unsigned short*)take(92160 * 2);
  float* BiF   = (float*)take(256);
  float* BbF   = (float*)take(512);
  float* AF    = (float*)take(32);
  float* WlF   = (float*)take(192);
  float* R1 = (float*)take((size_t)NSLICE * HW * 4);            // xr2 f32 (inv)
  unsigned short* B1 = (unsigned short*)take((size_t)NSLICE * HW * 2);  // dct2f out | angvi out
  unsigned short* B2 = (unsigned short*)take((size_t)NSLICE * HW * 2);  // angu out
  float* R3 = (float*)take((size_t)NSLICE * HW * 4);            // xf2b bf16 | xrb f32
  unsigned short* braw0 = (unsigned short*)take((size_t)81 * 16 * HW * 2);
  unsigned short* braw1 = (unsigned short*)take((size_t)81 * 16 * HW * 2);
  unsigned short* xf2b = (unsigned short*)R3;          // 10.6 MB < 15.9 MB
  float* xrb = R3;

  k_init<<<360, 256, 0, stream>>>(P, DaF, TFhi, TFlo, TIhi, TIlo,
                                  Wmf, BiF, BbF, AF, WlF);
  // fused forward spatial DCT (per-slice MFMA split-bf16) -> bf16
  k_dct2<<<243, 256, 0, stream>>>(x, TFhi, TFlo, nullptr, nullptr, B1);
  // forward angular DCT, separable, bf16 intermediates
  k_angu<<<1728, 256, 0, stream>>>(B1, DaF, B2);
  k_angv<<<1728, 256, 0, stream>>>(B2, DaF, xf2b);
  // branch convs (MFMA implicit GEMM; act-forwarding; sel2 fuses 1x1 epi)
  k_conv<<<dim3(16, 81), 512, 0, stream>>>(xf2b, nullptr, nullptr, Wmf,
                                           BiF, BbF, AF, WlF, 0, braw0, nullptr);
  k_conv<<<dim3(16, 81), 512, 0, stream>>>(braw0, braw0, nullptr, Wmf,
                                           BiF, BbF, AF, WlF, 1, braw1, nullptr);
  k_conv<<<dim3(16, 81), 512, 0, stream>>>(braw1, braw1, braw0, Wmf,
                                           BiF, BbF, AF, WlF, 2, nullptr, xrb);
  // inverse angular DCT, separable (band scatter in pass 1), bf16 mid
  k_angvi<<<1728, 256, 0, stream>>>(xrb, DaF, B1);
  k_angui<<<1728, 256, 0, stream>>>(B1, DaF, R1);
  // fused inverse spatial DCT + residual add (f32 out)
  k_dct2<<<243, 256, 0, stream>>>(R1, TIhi, TIlo, x, (float*)d_out, nullptr);
}